// Round 5
// baseline (869.447 us; speedup 1.0000x reference)
//
#include <hip/hip_runtime.h>
#include <math.h>

#define Bdim 8
#define Sdim 1024
#define Hdim 1024
#define NHd 16
#define HDd 64
#define N3H 3072

// ws layout (ushort elements)
#define Q_OFF   0u
#define K_OFF   16777216u
#define V_OFF   33554432u
#define WH_OFF  41943040u
#define WL_OFF  45088768u
// d_out scratch layout (ushort elements): Ahi, Alo
#define AHI_OFF 0u
#define ALO_OFF 8388608u

typedef __bf16 bf16x8 __attribute__((ext_vector_type(8)));
typedef float  f32x4  __attribute__((ext_vector_type(4)));

__device__ __forceinline__ unsigned short f2bf(float x) {
  unsigned b = __builtin_bit_cast(unsigned, x);
  return (unsigned short)((b + 0x7FFFu + ((b >> 16) & 1u)) >> 16);
}
__device__ __forceinline__ float bf2f(unsigned short h) {
  unsigned b = ((unsigned)h) << 16;
  return __builtin_bit_cast(float, b);
}
__device__ __forceinline__ void split_hl(float v, unsigned short& h, unsigned short& l) {
  h = f2bf(v);
  l = f2bf(v - bf2f(h));
}
__device__ __forceinline__ void async16(void* lds, const void* g) {
  __builtin_amdgcn_global_load_lds((const __attribute__((address_space(1))) unsigned int*)g,
                                   (__attribute__((address_space(3))) unsigned int*)lds, 16, 0, 0);
}

// ---------- fused convert: A -> hi/lo planes (d_out scratch); W -> W^T hi/lo (ws) ----------
__global__ __launch_bounds__(256) void convert_AW(
    const float* __restrict__ A, const float* __restrict__ W,
    unsigned short* __restrict__ aout, unsigned short* __restrict__ ws)
{
  __shared__ float T[64][65];
  const int tid = threadIdx.x;
  int bid = blockIdx.x;
  if (bid < 4096) {
    size_t i = ((size_t)bid * 256 + tid) * 8;
    float4 a0 = *(const float4*)&A[i];
    float4 a1 = *(const float4*)&A[i + 4];
    float av[8] = {a0.x, a0.y, a0.z, a0.w, a1.x, a1.y, a1.z, a1.w};
    unsigned short h[8], l[8];
    #pragma unroll
    for (int j = 0; j < 8; ++j) split_hl(av[j], h[j], l[j]);
    *(uint4*)&aout[AHI_OFF + i] = *(uint4*)h;
    *(uint4*)&aout[ALO_OFF + i] = *(uint4*)l;
    return;
  }
  bid -= 4096;
  const int n0 = (bid % (N3H / 64)) * 64;
  const int k0 = (bid / (N3H / 64)) * 64;
  #pragma unroll
  for (int r = 0; r < 4; ++r) {
    int k = r * 16 + (tid >> 4);
    int n = (tid & 15) * 4;
    float4 v = *(const float4*)&W[(size_t)(k0 + k) * N3H + n0 + n];
    T[k][n + 0] = v.x; T[k][n + 1] = v.y; T[k][n + 2] = v.z; T[k][n + 3] = v.w;
  }
  __syncthreads();
  int n = tid >> 2;
  int kl = (tid & 3) * 16;
  unsigned short h[16], l[16];
  #pragma unroll
  for (int i = 0; i < 16; ++i) split_hl(T[kl + i][n], h[i], l[i]);
  size_t base = (size_t)(n0 + n) * 1024 + k0 + kl;
  *(uint4*)&ws[WH_OFF + base]     = *(uint4*)&h[0];
  *(uint4*)&ws[WH_OFF + base + 8] = *(uint4*)&h[8];
  *(uint4*)&ws[WL_OFF + base]     = *(uint4*)&l[0];
  *(uint4*)&ws[WL_OFF + base + 8] = *(uint4*)&l[8];
}

// ---------- MFMA QKV GEMM: C = A(8192x1024) * W(1024x3072) + bias ----------
__global__ __launch_bounds__(256, 2) void qkv_mfma(
    const unsigned short* __restrict__ ao,
    const unsigned short* __restrict__ ws,
    const float* __restrict__ bias,
    unsigned short* __restrict__ wso)
{
  __shared__ unsigned short sA[2][128 * 32];
  __shared__ unsigned short sB[2][128 * 32];

  const int tid  = threadIdx.x;
  const int wave = tid >> 6;
  const int lane = tid & 63;
  const int l16  = lane & 15;
  const int quad = lane >> 4;

  const int n0 = blockIdx.x * 128;
  const int m0 = blockIdx.y * 128;
  const int wm = (wave >> 1) * 64;
  const int wn = (wave & 1) * 64;

  const unsigned short* Ah = ao + AHI_OFF;
  const unsigned short* Al = ao + ALO_OFF;
  const unsigned short* Wh = ws + WH_OFF;
  const unsigned short* Wl = ws + WL_OFF;

  f32x4 acc[4][4];
  #pragma unroll
  for (int i = 0; i < 4; ++i)
    #pragma unroll
    for (int j = 0; j < 4; ++j) acc[i][j] = (f32x4){0.f, 0.f, 0.f, 0.f};

  for (int kt = 0; kt < 1024; kt += 32) {
    __syncthreads();
    #pragma unroll
    for (int r = 0; r < 2; ++r) {
      int chunk = r * 256 + tid;
      int row = chunk >> 2;
      int c8  = (chunk & 3) << 3;
      int ldsoff = (r * 256 + wave * 64) * 8;
      async16(&sA[0][ldsoff], &Ah[(size_t)(m0 + row) * 1024 + kt + c8]);
      async16(&sA[1][ldsoff], &Al[(size_t)(m0 + row) * 1024 + kt + c8]);
      async16(&sB[0][ldsoff], &Wh[(size_t)(n0 + row) * 1024 + kt + c8]);
      async16(&sB[1][ldsoff], &Wl[(size_t)(n0 + row) * 1024 + kt + c8]);
    }
    __syncthreads();

    bf16x8 af[4][2], bf[4][2];
    #pragma unroll
    for (int i = 0; i < 4; ++i) {
      int row = wm + i * 16 + l16;
      af[i][0] = *(const bf16x8*)&sA[0][row * 32 + quad * 8];
      af[i][1] = *(const bf16x8*)&sA[1][row * 32 + quad * 8];
    }
    #pragma unroll
    for (int j = 0; j < 4; ++j) {
      int row = wn + j * 16 + l16;
      bf[j][0] = *(const bf16x8*)&sB[0][row * 32 + quad * 8];
      bf[j][1] = *(const bf16x8*)&sB[1][row * 32 + quad * 8];
    }
    #pragma unroll
    for (int i = 0; i < 4; ++i)
      #pragma unroll
      for (int j = 0; j < 4; ++j) {
        acc[i][j] = __builtin_amdgcn_mfma_f32_16x16x32_bf16(af[i][0], bf[j][0], acc[i][j], 0, 0, 0);
        acc[i][j] = __builtin_amdgcn_mfma_f32_16x16x32_bf16(af[i][1], bf[j][0], acc[i][j], 0, 0, 0);
        acc[i][j] = __builtin_amdgcn_mfma_f32_16x16x32_bf16(af[i][0], bf[j][1], acc[i][j], 0, 0, 0);
      }
  }

  const int ncol0 = n0 + wn;
  const int which = (ncol0 >> 6) % 3;
  const int head  = ncol0 / 192;
  const int mrow0 = m0 + wm;
  const int bb = mrow0 >> 10;
  const int sb = mrow0 & 1023;

  float bs[4];
  #pragma unroll
  for (int j = 0; j < 4; ++j) bs[j] = bias[ncol0 + j * 16 + l16];

  if (which < 2) {
    unsigned short* dst = wso + (which ? K_OFF : Q_OFF) +
        ((size_t)(bb * NHd + head) * Sdim + sb) * 128;
    #pragma unroll
    for (int i = 0; i < 4; ++i)
      #pragma unroll
      for (int j = 0; j < 4; ++j) {
        int d = j * 16 + l16;
        #pragma unroll
        for (int r = 0; r < 4; ++r) {
          int s = i * 16 + quad * 4 + r;
          float v = acc[i][j][r] + bs[j];
          unsigned short h, l;
          split_hl(v, h, l);
          dst[(size_t)s * 128 + d]      = h;
          dst[(size_t)s * 128 + 64 + d] = l;
        }
      }
  } else {
    unsigned short* dst = wso + V_OFF + (size_t)(bb * NHd + head) * HDd * Sdim;
    #pragma unroll
    for (int i = 0; i < 4; ++i)
      #pragma unroll
      for (int j = 0; j < 4; ++j) {
        int d = j * 16 + l16;
        int s0 = sb + i * 16 + quad * 4;
        unsigned short p[4];
        #pragma unroll
        for (int r = 0; r < 4; ++r) p[r] = f2bf(acc[i][j][r] + bs[j]);
        *(uint2*)&dst[(size_t)d * Sdim + s0] = *(uint2*)p;
      }
  }
}

// ---------------- MFMA flash attention: 128 queries/block ----------------
// 4 waves; wave w owns 2 q-subtiles (rows w*32+t*16 .. +16). K/V tiles of 64
// keys staged per iteration and reused by both subtiles. QK^T = 3-term split
// (hi·hi + lo·hi + hi·lo). Mask row preloaded. Q frags direct from global.
__global__ __launch_bounds__(256, 4) void attn_mfma(
    const unsigned short* __restrict__ qhl,
    const unsigned short* __restrict__ khl,
    const unsigned short* __restrict__ vt,
    const int* __restrict__ mask,
    float* __restrict__ out)
{
  __shared__ unsigned short Ks[64][136];
  __shared__ unsigned short Vs[64][72];
  __shared__ unsigned short Pw[4][16][72];
  __shared__ float msks[1024];

  const int tid  = threadIdx.x;
  const int wave = tid >> 6;
  const int lane = tid & 63;
  const int l16  = lane & 15;
  const int quad = lane >> 4;

  // bh fastest (stride 128 blocks per q-tile) -> all q-tiles of a bh on one XCD
  const int bh = blockIdx.x & 127;
  const int qt = blockIdx.x >> 7;
  const int bb = bh >> 4;
  const int q0 = qt * 128;

  // preload mask row for this batch
  {
    int4 mv = *(const int4*)&mask[bb * Sdim + tid * 4];
    msks[tid * 4 + 0] = mv.x ? 1.f : 0.f;
    msks[tid * 4 + 1] = mv.y ? 1.f : 0.f;
    msks[tid * 4 + 2] = mv.z ? 1.f : 0.f;
    msks[tid * 4 + 3] = mv.w ? 1.f : 0.f;
  }

  // Q fragments direct from global
  bf16x8 qf[2][4];
  #pragma unroll
  for (int t = 0; t < 2; ++t) {
    int row = q0 + wave * 32 + t * 16 + l16;
    const unsigned short* src = qhl + ((size_t)bh * Sdim + row) * 128;
    #pragma unroll
    for (int kk = 0; kk < 4; ++kk)
      qf[t][kk] = *(const bf16x8*)&src[kk * 32 + quad * 8];
  }

  f32x4 O[2][4];
  float mrow[2][4], lrow[2][4];
  #pragma unroll
  for (int t = 0; t < 2; ++t)
    #pragma unroll
    for (int d = 0; d < 4; ++d) {
      O[t][d] = (f32x4){0.f, 0.f, 0.f, 0.f};
      mrow[t][d] = -INFINITY;
      lrow[t][d] = 0.f;
    }

  #pragma unroll 1
  for (int kt = 0; kt < Sdim / 64; ++kt) {
    __syncthreads();
    {
      int row = tid >> 2, seg = tid & 3;
      const unsigned short* src = khl + ((size_t)bh * Sdim + kt * 64 + row) * 128;
      #pragma unroll
      for (int i = 0; i < 4; ++i) {
        int c = seg * 32 + i * 8;
        *(uint4*)&Ks[row][c] = *(const uint4*)&src[c];
      }
    }
    {
      int d = tid >> 2, part = tid & 3;
      const unsigned short* src = vt + ((size_t)bh * HDd + d) * Sdim + kt * 64;
      *(uint4*)&Vs[d][part * 16]     = *(const uint4*)&src[part * 16];
      *(uint4*)&Vs[d][part * 16 + 8] = *(const uint4*)&src[part * 16 + 8];
    }
    __syncthreads();

    #pragma unroll 1
    for (int t = 0; t < 2; ++t) {
      f32x4 sc[4];
      #pragma unroll
      for (int ns = 0; ns < 4; ++ns) {
        f32x4 c = {0.f, 0.f, 0.f, 0.f};
        int krow = ns * 16 + l16;
        bf16x8 kf[4];
        #pragma unroll
        for (int kk = 0; kk < 4; ++kk)
          kf[kk] = *(const bf16x8*)&Ks[krow][kk * 32 + quad * 8];
        c = __builtin_amdgcn_mfma_f32_16x16x32_bf16(qf[t][0], kf[0], c, 0, 0, 0);
        c = __builtin_amdgcn_mfma_f32_16x16x32_bf16(qf[t][1], kf[1], c, 0, 0, 0);
        c = __builtin_amdgcn_mfma_f32_16x16x32_bf16(qf[t][2], kf[0], c, 0, 0, 0);
        c = __builtin_amdgcn_mfma_f32_16x16x32_bf16(qf[t][3], kf[1], c, 0, 0, 0);
        c = __builtin_amdgcn_mfma_f32_16x16x32_bf16(qf[t][0], kf[2], c, 0, 0, 0);
        c = __builtin_amdgcn_mfma_f32_16x16x32_bf16(qf[t][1], kf[3], c, 0, 0, 0);
        sc[ns] = c;
      }

      float rmax[4] = {-INFINITY, -INFINITY, -INFINITY, -INFINITY};
      #pragma unroll
      for (int ns = 0; ns < 4; ++ns) {
        float mk = msks[kt * 64 + ns * 16 + l16];
        #pragma unroll
        for (int r = 0; r < 4; ++r) {
          float s = (mk != 0.f) ? -10000.f : sc[ns][r] * 8.f;
          sc[ns][r] = s;
          rmax[r] = fmaxf(rmax[r], s);
        }
      }
      #pragma unroll
      for (int r = 0; r < 4; ++r) {
        float v = rmax[r];
        v = fmaxf(v, __shfl_xor(v, 1, 16));
        v = fmaxf(v, __shfl_xor(v, 2, 16));
        v = fmaxf(v, __shfl_xor(v, 4, 16));
        v = fmaxf(v, __shfl_xor(v, 8, 16));
        rmax[r] = v;
      }

      float alpha[4];
      #pragma unroll
      for (int r = 0; r < 4; ++r) {
        float mn = fmaxf(mrow[t][r], rmax[r]);
        alpha[r] = __expf(mrow[t][r] - mn);
        mrow[t][r] = mn;
        lrow[t][r] *= alpha[r];
      }
      #pragma unroll
      for (int d = 0; d < 4; ++d)
        #pragma unroll
        for (int r = 0; r < 4; ++r) O[t][d][r] *= alpha[r];

      float rsum[4] = {0.f, 0.f, 0.f, 0.f};
      #pragma unroll
      for (int ns = 0; ns < 4; ++ns) {
        #pragma unroll
        for (int r = 0; r < 4; ++r) {
          float p = __expf(sc[ns][r] - mrow[t][r]);
          rsum[r] += p;
          Pw[wave][quad * 4 + r][ns * 16 + l16] = f2bf(p);
        }
      }
      #pragma unroll
      for (int r = 0; r < 4; ++r) {
        float v = rsum[r];
        v += __shfl_xor(v, 1, 16);
        v += __shfl_xor(v, 2, 16);
        v += __shfl_xor(v, 4, 16);
        v += __shfl_xor(v, 8, 16);
        lrow[t][r] += v;
      }

      bf16x8 pf[2];
      #pragma unroll
      for (int kk = 0; kk < 2; ++kk)
        pf[kk] = *(const bf16x8*)&Pw[wave][l16][kk * 32 + quad * 8];
      #pragma unroll
      for (int d = 0; d < 4; ++d) {
        int vrow = d * 16 + l16;
        #pragma unroll
        for (int kk = 0; kk < 2; ++kk) {
          bf16x8 vf = *(const bf16x8*)&Vs[vrow][kk * 32 + quad * 8];
          O[t][d] = __builtin_amdgcn_mfma_f32_16x16x32_bf16(pf[kk], vf, O[t][d], 0, 0, 0);
        }
      }
    }
  }

  const int h = bh & 15;
  #pragma unroll
  for (int t = 0; t < 2; ++t)
    #pragma unroll
    for (int r = 0; r < 4; ++r) {
      float inv = 1.f / lrow[t][r];
      int q = q0 + wave * 32 + t * 16 + quad * 4 + r;
      float* dst = out + ((size_t)bb * Sdim + q) * Hdim + h * HDd;
      #pragma unroll
      for (int d = 0; d < 4; ++d)
        dst[d * 16 + l16] = O[t][d][r] * inv;
    }
}

extern "C" void kernel_launch(void* const* d_in, const int* in_sizes, int n_in,
                              void* d_out, int out_size, void* d_ws, size_t ws_size,
                              hipStream_t stream) {
  const float* hs   = (const float*)d_in[0];
  const int*   mask = (const int*)d_in[1];
  const float* w    = (const float*)d_in[2];
  const float* bias = (const float*)d_in[3];
  float* out = (float*)d_out;
  unsigned short* ws = (unsigned short*)d_ws;
  unsigned short* ao = (unsigned short*)d_out;   // A hi/lo scratch, overwritten by attn

  convert_AW<<<4096 + (N3H / 64) * (1024 / 64), 256, 0, stream>>>(hs, w, ao, ws);

  qkv_mfma<<<dim3(N3H / 128, 8192 / 128), 256, 0, stream>>>(ao, ws, bias, ws);

  attn_mfma<<<Bdim * NHd * (Sdim / 128), 256, 0, stream>>>(
      ws + Q_OFF, ws + K_OFF, ws + V_OFF, mask, out);
}

// Round 6
// 395.517 us; speedup vs baseline: 2.1983x; 2.1983x over previous
//
#include <hip/hip_runtime.h>
#include <math.h>

#define Bdim 8
#define Sdim 1024
#define Hdim 1024
#define NHd 16
#define HDd 64
#define N3H 3072

// ws layout (ushort elements)
// Q: [bh][s][128] row-major (hi|lo). K: [bh][16 tiles][8192] fragment-ordered.
// V: [bh][16 tiles][4096] fragment-ordered. W^T hi/lo planes after.
#define Q_OFF   0u
#define K_OFF   16777216u
#define V_OFF   33554432u
#define WH_OFF  41943040u
#define WL_OFF  45088768u
// d_out scratch layout (ushort elements): Ahi, Alo
#define AHI_OFF 0u
#define ALO_OFF 8388608u

typedef __bf16 bf16x8 __attribute__((ext_vector_type(8)));
typedef float  f32x4  __attribute__((ext_vector_type(4)));

__device__ __forceinline__ unsigned short f2bf(float x) {
  unsigned b = __builtin_bit_cast(unsigned, x);
  return (unsigned short)((b + 0x7FFFu + ((b >> 16) & 1u)) >> 16);
}
__device__ __forceinline__ float bf2f(unsigned short h) {
  unsigned b = ((unsigned)h) << 16;
  return __builtin_bit_cast(float, b);
}
__device__ __forceinline__ void split_hl(float v, unsigned short& h, unsigned short& l) {
  h = f2bf(v);
  l = f2bf(v - bf2f(h));
}
__device__ __forceinline__ void async16(void* lds, const void* g) {
  __builtin_amdgcn_global_load_lds((const __attribute__((address_space(1))) unsigned int*)g,
                                   (__attribute__((address_space(3))) unsigned int*)lds, 16, 0, 0);
}

// ---------- fused convert: A -> hi/lo planes (d_out scratch); W -> W^T hi/lo (ws) ----------
__global__ __launch_bounds__(256) void convert_AW(
    const float* __restrict__ A, const float* __restrict__ W,
    unsigned short* __restrict__ aout, unsigned short* __restrict__ ws)
{
  __shared__ float T[64][65];
  const int tid = threadIdx.x;
  int bid = blockIdx.x;
  if (bid < 4096) {
    size_t i = ((size_t)bid * 256 + tid) * 8;
    float4 a0 = *(const float4*)&A[i];
    float4 a1 = *(const float4*)&A[i + 4];
    float av[8] = {a0.x, a0.y, a0.z, a0.w, a1.x, a1.y, a1.z, a1.w};
    unsigned short h[8], l[8];
    #pragma unroll
    for (int j = 0; j < 8; ++j) split_hl(av[j], h[j], l[j]);
    *(uint4*)&aout[AHI_OFF + i] = *(uint4*)h;
    *(uint4*)&aout[ALO_OFF + i] = *(uint4*)l;
    return;
  }
  bid -= 4096;
  const int n0 = (bid % (N3H / 64)) * 64;
  const int k0 = (bid / (N3H / 64)) * 64;
  #pragma unroll
  for (int r = 0; r < 4; ++r) {
    int k = r * 16 + (tid >> 4);
    int n = (tid & 15) * 4;
    float4 v = *(const float4*)&W[(size_t)(k0 + k) * N3H + n0 + n];
    T[k][n + 0] = v.x; T[k][n + 1] = v.y; T[k][n + 2] = v.z; T[k][n + 3] = v.w;
  }
  __syncthreads();
  int n = tid >> 2;
  int kl = (tid & 3) * 16;
  unsigned short h[16], l[16];
  #pragma unroll
  for (int i = 0; i < 16; ++i) split_hl(T[kl + i][n], h[i], l[i]);
  size_t base = (size_t)(n0 + n) * 1024 + k0 + kl;
  *(uint4*)&ws[WH_OFF + base]     = *(uint4*)&h[0];
  *(uint4*)&ws[WH_OFF + base + 8] = *(uint4*)&h[8];
  *(uint4*)&ws[WL_OFF + base]     = *(uint4*)&l[0];
  *(uint4*)&ws[WL_OFF + base + 8] = *(uint4*)&l[8];
}

// ---------- MFMA QKV GEMM: C = A(8192x1024) * W(1024x3072) + bias ----------
__global__ __launch_bounds__(256, 2) void qkv_mfma(
    const unsigned short* __restrict__ ao,
    const unsigned short* __restrict__ ws,
    const float* __restrict__ bias,
    unsigned short* __restrict__ wso)
{
  __shared__ unsigned short sA[2][128 * 32];
  __shared__ unsigned short sB[2][128 * 32];

  const int tid  = threadIdx.x;
  const int wave = tid >> 6;
  const int lane = tid & 63;
  const int l16  = lane & 15;
  const int quad = lane >> 4;

  const int n0 = blockIdx.x * 128;
  const int m0 = blockIdx.y * 128;
  const int wm = (wave >> 1) * 64;
  const int wn = (wave & 1) * 64;

  const unsigned short* Ah = ao + AHI_OFF;
  const unsigned short* Al = ao + ALO_OFF;
  const unsigned short* Wh = ws + WH_OFF;
  const unsigned short* Wl = ws + WL_OFF;

  f32x4 acc[4][4];
  #pragma unroll
  for (int i = 0; i < 4; ++i)
    #pragma unroll
    for (int j = 0; j < 4; ++j) acc[i][j] = (f32x4){0.f, 0.f, 0.f, 0.f};

  for (int kt = 0; kt < 1024; kt += 32) {
    __syncthreads();
    #pragma unroll
    for (int r = 0; r < 2; ++r) {
      int chunk = r * 256 + tid;
      int row = chunk >> 2;
      int c8  = (chunk & 3) << 3;
      int ldsoff = (r * 256 + wave * 64) * 8;
      async16(&sA[0][ldsoff], &Ah[(size_t)(m0 + row) * 1024 + kt + c8]);
      async16(&sA[1][ldsoff], &Al[(size_t)(m0 + row) * 1024 + kt + c8]);
      async16(&sB[0][ldsoff], &Wh[(size_t)(n0 + row) * 1024 + kt + c8]);
      async16(&sB[1][ldsoff], &Wl[(size_t)(n0 + row) * 1024 + kt + c8]);
    }
    __syncthreads();

    bf16x8 af[4][2], bf[4][2];
    #pragma unroll
    for (int i = 0; i < 4; ++i) {
      int row = wm + i * 16 + l16;
      af[i][0] = *(const bf16x8*)&sA[0][row * 32 + quad * 8];
      af[i][1] = *(const bf16x8*)&sA[1][row * 32 + quad * 8];
    }
    #pragma unroll
    for (int j = 0; j < 4; ++j) {
      int row = wn + j * 16 + l16;
      bf[j][0] = *(const bf16x8*)&sB[0][row * 32 + quad * 8];
      bf[j][1] = *(const bf16x8*)&sB[1][row * 32 + quad * 8];
    }
    #pragma unroll
    for (int i = 0; i < 4; ++i)
      #pragma unroll
      for (int j = 0; j < 4; ++j) {
        acc[i][j] = __builtin_amdgcn_mfma_f32_16x16x32_bf16(af[i][0], bf[j][0], acc[i][j], 0, 0, 0);
        acc[i][j] = __builtin_amdgcn_mfma_f32_16x16x32_bf16(af[i][1], bf[j][0], acc[i][j], 0, 0, 0);
        acc[i][j] = __builtin_amdgcn_mfma_f32_16x16x32_bf16(af[i][0], bf[j][1], acc[i][j], 0, 0, 0);
      }
  }

  const int ncol0 = n0 + wn;
  const int which = (ncol0 >> 6) % 3;
  const int head  = ncol0 / 192;
  const int mrow0 = m0 + wm;
  const int bb = mrow0 >> 10;
  const int sb = mrow0 & 1023;
  const int bh = bb * NHd + head;

  float bs[4];
  #pragma unroll
  for (int j = 0; j < 4; ++j) bs[j] = bias[ncol0 + j * 16 + l16];

  if (which == 0) {
    // Q: row-major [bh][s][128], hi at d, lo at 64+d
    unsigned short* dst = wso + Q_OFF + ((size_t)bh * Sdim + sb) * 128;
    #pragma unroll
    for (int i = 0; i < 4; ++i)
      #pragma unroll
      for (int j = 0; j < 4; ++j) {
        int d = j * 16 + l16;
        #pragma unroll
        for (int r = 0; r < 4; ++r) {
          int s = i * 16 + quad * 4 + r;
          unsigned short h, l;
          split_hl(acc[i][j][r] + bs[j], h, l);
          dst[(size_t)s * 128 + d]      = h;
          dst[(size_t)s * 128 + 64 + d] = l;
        }
      }
  } else if (which == 1) {
    // K: fragment-ordered tile (64 keys x 128), tile = sb/64
    unsigned short* dst = wso + K_OFF + (size_t)bh * 131072 + (size_t)(sb >> 6) * 8192;
    #pragma unroll
    for (int i = 0; i < 4; ++i)
      #pragma unroll
      for (int j = 0; j < 4; ++j) {
        int c = j * 16 + l16;     // hi column
        #pragma unroll
        for (int r = 0; r < 4; ++r) {
          int sp = i * 16 + quad * 4 + r;
          int idx = ((((sp >> 4) * 4 + (c >> 5)) * 64 + ((c >> 3) & 3) * 16 + (sp & 15)) << 3) + (c & 7);
          unsigned short h, l;
          split_hl(acc[i][j][r] + bs[j], h, l);
          dst[idx]        = h;
          dst[idx + 1024] = l;    // lo: c+64 -> +2 chunk-groups = +1024 ushorts
        }
      }
  } else {
    // V: fragment-ordered tile (64 d x 64 keys), tile = sb/64
    unsigned short* dst = wso + V_OFF + (size_t)bh * 65536 + (size_t)(sb >> 6) * 4096;
    #pragma unroll
    for (int i = 0; i < 4; ++i)
      #pragma unroll
      for (int j = 0; j < 4; ++j) {
        int dr = j * 16 + l16;
        int ky = i * 16 + quad * 4;
        int idx = ((((dr >> 4) * 2 + (ky >> 5)) * 64 + ((ky >> 3) & 3) * 16 + (dr & 15)) << 3) + (ky & 7);
        unsigned short p[4];
        #pragma unroll
        for (int r = 0; r < 4; ++r) p[r] = f2bf(acc[i][j][r] + bs[j]);
        *(uint2*)&dst[idx] = *(uint2*)p;
      }
  }
}

// ---------------- MFMA flash attention: 64 q/block, async dbuf K/V ----------------
__global__ __launch_bounds__(256, 2) void attn_mfma(
    const unsigned short* __restrict__ qhl,
    const unsigned short* __restrict__ khl,   // fragment-ordered tiles
    const unsigned short* __restrict__ vt,    // fragment-ordered tiles
    const int* __restrict__ mask,
    float* __restrict__ out)
{
  __shared__ unsigned short Ks[2][8192];
  __shared__ unsigned short Vs[2][4096];
  __shared__ unsigned short Pw[4][1024];
  __shared__ float msks[1024];

  const int tid  = threadIdx.x;
  const int wave = tid >> 6;
  const int lane = tid & 63;
  const int l16  = lane & 15;
  const int quad = lane >> 4;

  const int qt = blockIdx.x & 15;       // qt fastest: 16 blocks/bh adjacent -> L2 reuse
  const int bh = blockIdx.x >> 4;
  const int bb = bh >> 4;
  const int q0 = qt * 64;

  const unsigned short* kplane = khl + (size_t)bh * 131072;
  const unsigned short* vplane = vt  + (size_t)bh * 65536;

  // prefetch tile 0 (async, contiguous)
  #pragma unroll
  for (int r = 0; r < 4; ++r)
    async16(&Ks[0][(r * 256 + tid) * 8], &kplane[(size_t)(r * 256 + tid) * 8]);
  #pragma unroll
  for (int r = 0; r < 2; ++r)
    async16(&Vs[0][(r * 256 + tid) * 8], &vplane[(size_t)(r * 256 + tid) * 8]);

  // mask row preload (once)
  {
    int4 mv = *(const int4*)&mask[bb * Sdim + tid * 4];
    msks[tid * 4 + 0] = mv.x ? 1.f : 0.f;
    msks[tid * 4 + 1] = mv.y ? 1.f : 0.f;
    msks[tid * 4 + 2] = mv.z ? 1.f : 0.f;
    msks[tid * 4 + 3] = mv.w ? 1.f : 0.f;
  }

  // Q fragments direct from global
  bf16x8 qf[4];
  {
    int row = q0 + wave * 16 + l16;
    const unsigned short* src = qhl + ((size_t)bh * Sdim + row) * 128;
    #pragma unroll
    for (int kk = 0; kk < 4; ++kk)
      qf[kk] = *(const bf16x8*)&src[kk * 32 + quad * 8];
  }

  f32x4 O[4] = {{0.f,0.f,0.f,0.f},{0.f,0.f,0.f,0.f},{0.f,0.f,0.f,0.f},{0.f,0.f,0.f,0.f}};
  float mrow[4] = {-INFINITY, -INFINITY, -INFINITY, -INFINITY};
  float lrow[4] = {0.f, 0.f, 0.f, 0.f};

  __syncthreads();   // tile 0 + mask visible

  #pragma unroll 1
  for (int kt = 0; kt < 16; ++kt) {
    const int cur = kt & 1;
    // prefetch next tile into the other buffer (drained by end-of-iter barrier)
    if (kt < 15) {
      const unsigned short* ksrc = kplane + (size_t)(kt + 1) * 8192;
      const unsigned short* vsrc = vplane + (size_t)(kt + 1) * 4096;
      #pragma unroll
      for (int r = 0; r < 4; ++r)
        async16(&Ks[cur ^ 1][(r * 256 + tid) * 8], &ksrc[(size_t)(r * 256 + tid) * 8]);
      #pragma unroll
      for (int r = 0; r < 2; ++r)
        async16(&Vs[cur ^ 1][(r * 256 + tid) * 8], &vsrc[(size_t)(r * 256 + tid) * 8]);
    }

    // QK^T: 3-term split (hi·hi + lo·hi + hi·lo); conflict-free lane-contiguous reads
    f32x4 sc[4];
    #pragma unroll
    for (int ns = 0; ns < 4; ++ns) {
      f32x4 c = {0.f, 0.f, 0.f, 0.f};
      bf16x8 kf0 = *(const bf16x8*)&Ks[cur][((ns * 4 + 0) * 64 + lane) * 8];
      bf16x8 kf1 = *(const bf16x8*)&Ks[cur][((ns * 4 + 1) * 64 + lane) * 8];
      bf16x8 kf2 = *(const bf16x8*)&Ks[cur][((ns * 4 + 2) * 64 + lane) * 8];
      bf16x8 kf3 = *(const bf16x8*)&Ks[cur][((ns * 4 + 3) * 64 + lane) * 8];
      c = __builtin_amdgcn_mfma_f32_16x16x32_bf16(qf[0], kf0, c, 0, 0, 0);
      c = __builtin_amdgcn_mfma_f32_16x16x32_bf16(qf[1], kf1, c, 0, 0, 0);
      c = __builtin_amdgcn_mfma_f32_16x16x32_bf16(qf[2], kf0, c, 0, 0, 0);
      c = __builtin_amdgcn_mfma_f32_16x16x32_bf16(qf[3], kf1, c, 0, 0, 0);
      c = __builtin_amdgcn_mfma_f32_16x16x32_bf16(qf[0], kf2, c, 0, 0, 0);
      c = __builtin_amdgcn_mfma_f32_16x16x32_bf16(qf[1], kf3, c, 0, 0, 0);
      sc[ns] = c;
    }

    // mask + scale, row max
    float rmax[4] = {-INFINITY, -INFINITY, -INFINITY, -INFINITY};
    #pragma unroll
    for (int ns = 0; ns < 4; ++ns) {
      float mk = msks[kt * 64 + ns * 16 + l16];
      #pragma unroll
      for (int r = 0; r < 4; ++r) {
        float s = (mk != 0.f) ? -10000.f : sc[ns][r] * 8.f;
        sc[ns][r] = s;
        rmax[r] = fmaxf(rmax[r], s);
      }
    }
    #pragma unroll
    for (int r = 0; r < 4; ++r) {
      float v = rmax[r];
      v = fmaxf(v, __shfl_xor(v, 1, 16));
      v = fmaxf(v, __shfl_xor(v, 2, 16));
      v = fmaxf(v, __shfl_xor(v, 4, 16));
      v = fmaxf(v, __shfl_xor(v, 8, 16));
      rmax[r] = v;
    }

    float alpha[4];
    #pragma unroll
    for (int r = 0; r < 4; ++r) {
      float mn = fmaxf(mrow[r], rmax[r]);
      alpha[r] = __expf(mrow[r] - mn);
      mrow[r] = mn;
      lrow[r] *= alpha[r];
    }
    #pragma unroll
    for (int d = 0; d < 4; ++d)
      #pragma unroll
      for (int r = 0; r < 4; ++r) O[d][r] *= alpha[r];

    // exp, row-sum, write P (bf16) to per-wave LDS in A-fragment order
    float rsum[4] = {0.f, 0.f, 0.f, 0.f};
    #pragma unroll
    for (int ns = 0; ns < 4; ++ns) {
      int key = ns * 16 + l16;
      int cbase = (((key >> 5) * 4 + ((key >> 3) & 3)) * 16 + quad * 4) * 8 + (key & 7);
      #pragma unroll
      for (int r = 0; r < 4; ++r) {
        float p = __expf(sc[ns][r] - mrow[r]);
        rsum[r] += p;
        Pw[wave][cbase + r * 8] = f2bf(p);
      }
    }
    #pragma unroll
    for (int r = 0; r < 4; ++r) {
      float v = rsum[r];
      v += __shfl_xor(v, 1, 16);
      v += __shfl_xor(v, 2, 16);
      v += __shfl_xor(v, 4, 16);
      v += __shfl_xor(v, 8, 16);
      lrow[r] += v;
    }

    // P·V (wave-local; lane-contiguous reads)
    bf16x8 pf[2];
    #pragma unroll
    for (int kk = 0; kk < 2; ++kk)
      pf[kk] = *(const bf16x8*)&Pw[wave][((kk * 4 + quad) * 16 + l16) * 8];
    #pragma unroll
    for (int d = 0; d < 4; ++d)
      #pragma unroll
      for (int kk = 0; kk < 2; ++kk) {
        bf16x8 vf = *(const bf16x8*)&Vs[cur][((d * 2 + kk) * 64 + lane) * 8];
        O[d] = __builtin_amdgcn_mfma_f32_16x16x32_bf16(pf[kk], vf, O[d], 0, 0, 0);
      }

    __syncthreads();   // drains prefetch (vmcnt) + protects buffer reuse
  }

  // epilogue
  const int h = bh & 15;
  #pragma unroll
  for (int r = 0; r < 4; ++r) {
    float inv = 1.f / lrow[r];
    int q = q0 + wave * 16 + quad * 4 + r;
    float* dst = out + ((size_t)bb * Sdim + q) * Hdim + h * HDd;
    #pragma unroll
    for (int d = 0; d < 4; ++d)
      dst[d * 16 + l16] = O[d][r] * inv;
  }
}

extern "C" void kernel_launch(void* const* d_in, const int* in_sizes, int n_in,
                              void* d_out, int out_size, void* d_ws, size_t ws_size,
                              hipStream_t stream) {
  const float* hs   = (const float*)d_in[0];
  const int*   mask = (const int*)d_in[1];
  const float* w    = (const float*)d_in[2];
  const float* bias = (const float*)d_in[3];
  float* out = (float*)d_out;
  unsigned short* ws = (unsigned short*)d_ws;
  unsigned short* ao = (unsigned short*)d_out;   // A hi/lo scratch, overwritten by attn

  convert_AW<<<4096 + (N3H / 64) * (1024 / 64), 256, 0, stream>>>(hs, w, ao, ws);

  qkv_mfma<<<dim3(N3H / 128, 8192 / 128), 256, 0, stream>>>(ao, ws, bias, ws);

  attn_mfma<<<Bdim * NHd * (Sdim / 64), 256, 0, stream>>>(
      ws + Q_OFF, ws + K_OFF, ws + V_OFF, mask, out);
}

// Round 7
// 361.540 us; speedup vs baseline: 2.4048x; 1.0940x over previous
//
#include <hip/hip_runtime.h>
#include <math.h>

#define Bdim 8
#define Sdim 1024
#define Hdim 1024
#define NHd 16
#define HDd 64
#define N3H 3072

// ws layout (ushort elements)
// Q: [bh][s][128] row-major (hi|lo). K: [bh][16 tiles][8192] fragment-ordered.
// V: [bh][16 tiles][4096] fragment-ordered. W^T hi/lo planes after.
#define Q_OFF   0u
#define K_OFF   16777216u
#define V_OFF   33554432u
#define WH_OFF  41943040u
#define WL_OFF  45088768u
// d_out scratch layout (ushort elements): Ahi, Alo
#define AHI_OFF 0u
#define ALO_OFF 8388608u

typedef __bf16 bf16x8 __attribute__((ext_vector_type(8)));
typedef float  f32x4  __attribute__((ext_vector_type(4)));

__device__ __forceinline__ unsigned short f2bf(float x) {
  unsigned b = __builtin_bit_cast(unsigned, x);
  return (unsigned short)((b + 0x7FFFu + ((b >> 16) & 1u)) >> 16);
}
__device__ __forceinline__ float bf2f(unsigned short h) {
  unsigned b = ((unsigned)h) << 16;
  return __builtin_bit_cast(float, b);
}
__device__ __forceinline__ void split_hl(float v, unsigned short& h, unsigned short& l) {
  h = f2bf(v);
  l = f2bf(v - bf2f(h));
}
__device__ __forceinline__ void async16(void* lds, const void* g) {
  __builtin_amdgcn_global_load_lds((const __attribute__((address_space(1))) unsigned int*)g,
                                   (__attribute__((address_space(3))) unsigned int*)lds, 16, 0, 0);
}

// ---------- fused convert: A -> hi/lo planes (d_out scratch); W -> W^T hi/lo (ws) ----------
__global__ __launch_bounds__(256) void convert_AW(
    const float* __restrict__ A, const float* __restrict__ W,
    unsigned short* __restrict__ aout, unsigned short* __restrict__ ws)
{
  __shared__ float T[64][65];
  const int tid = threadIdx.x;
  int bid = blockIdx.x;
  if (bid < 4096) {
    size_t i = ((size_t)bid * 256 + tid) * 8;
    float4 a0 = *(const float4*)&A[i];
    float4 a1 = *(const float4*)&A[i + 4];
    float av[8] = {a0.x, a0.y, a0.z, a0.w, a1.x, a1.y, a1.z, a1.w};
    unsigned short h[8], l[8];
    #pragma unroll
    for (int j = 0; j < 8; ++j) split_hl(av[j], h[j], l[j]);
    *(uint4*)&aout[AHI_OFF + i] = *(uint4*)h;
    *(uint4*)&aout[ALO_OFF + i] = *(uint4*)l;
    return;
  }
  bid -= 4096;
  const int n0 = (bid % (N3H / 64)) * 64;
  const int k0 = (bid / (N3H / 64)) * 64;
  #pragma unroll
  for (int r = 0; r < 4; ++r) {
    int k = r * 16 + (tid >> 4);
    int n = (tid & 15) * 4;
    float4 v = *(const float4*)&W[(size_t)(k0 + k) * N3H + n0 + n];
    T[k][n + 0] = v.x; T[k][n + 1] = v.y; T[k][n + 2] = v.z; T[k][n + 3] = v.w;
  }
  __syncthreads();
  int n = tid >> 2;
  int kl = (tid & 3) * 16;
  unsigned short h[16], l[16];
  #pragma unroll
  for (int i = 0; i < 16; ++i) split_hl(T[kl + i][n], h[i], l[i]);
  size_t base = (size_t)(n0 + n) * 1024 + k0 + kl;
  *(uint4*)&ws[WH_OFF + base]     = *(uint4*)&h[0];
  *(uint4*)&ws[WH_OFF + base + 8] = *(uint4*)&h[8];
  *(uint4*)&ws[WL_OFF + base]     = *(uint4*)&l[0];
  *(uint4*)&ws[WL_OFF + base + 8] = *(uint4*)&l[8];
}

// ---------- MFMA QKV GEMM: C = A(8192x1024) * W(1024x3072) + bias ----------
__global__ __launch_bounds__(256, 2) void qkv_mfma(
    const unsigned short* __restrict__ ao,
    const unsigned short* __restrict__ ws,
    const float* __restrict__ bias,
    unsigned short* __restrict__ wso)
{
  __shared__ unsigned short sA[2][128 * 32];
  __shared__ unsigned short sB[2][128 * 32];

  const int tid  = threadIdx.x;
  const int wave = tid >> 6;
  const int lane = tid & 63;
  const int l16  = lane & 15;
  const int quad = lane >> 4;

  const int n0 = blockIdx.x * 128;
  const int m0 = blockIdx.y * 128;
  const int wm = (wave >> 1) * 64;
  const int wn = (wave & 1) * 64;

  const unsigned short* Ah = ao + AHI_OFF;
  const unsigned short* Al = ao + ALO_OFF;
  const unsigned short* Wh = ws + WH_OFF;
  const unsigned short* Wl = ws + WL_OFF;

  f32x4 acc[4][4];
  #pragma unroll
  for (int i = 0; i < 4; ++i)
    #pragma unroll
    for (int j = 0; j < 4; ++j) acc[i][j] = (f32x4){0.f, 0.f, 0.f, 0.f};

  for (int kt = 0; kt < 1024; kt += 32) {
    __syncthreads();
    #pragma unroll
    for (int r = 0; r < 2; ++r) {
      int chunk = r * 256 + tid;
      int row = chunk >> 2;
      int c8  = (chunk & 3) << 3;
      int ldsoff = (r * 256 + wave * 64) * 8;
      async16(&sA[0][ldsoff], &Ah[(size_t)(m0 + row) * 1024 + kt + c8]);
      async16(&sA[1][ldsoff], &Al[(size_t)(m0 + row) * 1024 + kt + c8]);
      async16(&sB[0][ldsoff], &Wh[(size_t)(n0 + row) * 1024 + kt + c8]);
      async16(&sB[1][ldsoff], &Wl[(size_t)(n0 + row) * 1024 + kt + c8]);
    }
    __syncthreads();

    bf16x8 af[4][2], bf[4][2];
    #pragma unroll
    for (int i = 0; i < 4; ++i) {
      int row = wm + i * 16 + l16;
      af[i][0] = *(const bf16x8*)&sA[0][row * 32 + quad * 8];
      af[i][1] = *(const bf16x8*)&sA[1][row * 32 + quad * 8];
    }
    #pragma unroll
    for (int j = 0; j < 4; ++j) {
      int row = wn + j * 16 + l16;
      bf[j][0] = *(const bf16x8*)&sB[0][row * 32 + quad * 8];
      bf[j][1] = *(const bf16x8*)&sB[1][row * 32 + quad * 8];
    }
    #pragma unroll
    for (int i = 0; i < 4; ++i)
      #pragma unroll
      for (int j = 0; j < 4; ++j) {
        acc[i][j] = __builtin_amdgcn_mfma_f32_16x16x32_bf16(af[i][0], bf[j][0], acc[i][j], 0, 0, 0);
        acc[i][j] = __builtin_amdgcn_mfma_f32_16x16x32_bf16(af[i][1], bf[j][0], acc[i][j], 0, 0, 0);
        acc[i][j] = __builtin_amdgcn_mfma_f32_16x16x32_bf16(af[i][0], bf[j][1], acc[i][j], 0, 0, 0);
      }
  }

  const int ncol0 = n0 + wn;
  const int which = (ncol0 >> 6) % 3;
  const int head  = ncol0 / 192;
  const int mrow0 = m0 + wm;
  const int bb = mrow0 >> 10;
  const int sb = mrow0 & 1023;
  const int bh = bb * NHd + head;

  float bs[4];
  #pragma unroll
  for (int j = 0; j < 4; ++j) bs[j] = bias[ncol0 + j * 16 + l16];

  if (which == 0) {
    unsigned short* dst = wso + Q_OFF + ((size_t)bh * Sdim + sb) * 128;
    #pragma unroll
    for (int i = 0; i < 4; ++i)
      #pragma unroll
      for (int j = 0; j < 4; ++j) {
        int d = j * 16 + l16;
        #pragma unroll
        for (int r = 0; r < 4; ++r) {
          int s = i * 16 + quad * 4 + r;
          unsigned short h, l;
          split_hl(acc[i][j][r] + bs[j], h, l);
          dst[(size_t)s * 128 + d]      = h;
          dst[(size_t)s * 128 + 64 + d] = l;
        }
      }
  } else if (which == 1) {
    unsigned short* dst = wso + K_OFF + (size_t)bh * 131072 + (size_t)(sb >> 6) * 8192;
    #pragma unroll
    for (int i = 0; i < 4; ++i)
      #pragma unroll
      for (int j = 0; j < 4; ++j) {
        int c = j * 16 + l16;
        #pragma unroll
        for (int r = 0; r < 4; ++r) {
          int sp = i * 16 + quad * 4 + r;
          int idx = ((((sp >> 4) * 4 + (c >> 5)) * 64 + ((c >> 3) & 3) * 16 + (sp & 15)) << 3) + (c & 7);
          unsigned short h, l;
          split_hl(acc[i][j][r] + bs[j], h, l);
          dst[idx]        = h;
          dst[idx + 1024] = l;
        }
      }
  } else {
    unsigned short* dst = wso + V_OFF + (size_t)bh * 65536 + (size_t)(sb >> 6) * 4096;
    #pragma unroll
    for (int i = 0; i < 4; ++i)
      #pragma unroll
      for (int j = 0; j < 4; ++j) {
        int dr = j * 16 + l16;
        int ky = i * 16 + quad * 4;
        int idx = ((((dr >> 4) * 2 + (ky >> 5)) * 64 + ((ky >> 3) & 3) * 16 + (dr & 15)) << 3) + (ky & 7);
        unsigned short p[4];
        #pragma unroll
        for (int r = 0; r < 4; ++r) p[r] = f2bf(acc[i][j][r] + bs[j]);
        *(uint2*)&dst[idx] = *(uint2*)p;
      }
  }
}

// -------- MFMA flash attention: 64 q/block, single-buffer async staging, 4 blk/CU --------
__global__ __launch_bounds__(256, 4) void attn_mfma(
    const unsigned short* __restrict__ qhl,
    const unsigned short* __restrict__ khl,   // fragment-ordered tiles
    const unsigned short* __restrict__ vt,    // fragment-ordered tiles
    const int* __restrict__ mask,
    float* __restrict__ out)
{
  __shared__ unsigned short Ks[8192];
  __shared__ unsigned short Vs[4096];
  __shared__ unsigned short Pw[4][1024];
  __shared__ float msks[1024];

  const int tid  = threadIdx.x;
  const int wave = tid >> 6;
  const int lane = tid & 63;
  const int l16  = lane & 15;
  const int quad = lane >> 4;

  // bh fastest (stride 128 ≡ 0 mod 8) -> all q-tiles of one bh on the same XCD
  const int bh = blockIdx.x & 127;
  const int qt = blockIdx.x >> 7;
  const int bb = bh >> 4;
  const int q0 = qt * 64;

  const unsigned short* kplane = khl + (size_t)bh * 131072;
  const unsigned short* vplane = vt  + (size_t)bh * 65536;

  // mask row preload (once)
  {
    int4 mv = *(const int4*)&mask[bb * Sdim + tid * 4];
    msks[tid * 4 + 0] = mv.x ? 1.f : 0.f;
    msks[tid * 4 + 1] = mv.y ? 1.f : 0.f;
    msks[tid * 4 + 2] = mv.z ? 1.f : 0.f;
    msks[tid * 4 + 3] = mv.w ? 1.f : 0.f;
  }

  // Q fragments direct from global
  bf16x8 qf[4];
  {
    int row = q0 + wave * 16 + l16;
    const unsigned short* src = qhl + ((size_t)bh * Sdim + row) * 128;
    #pragma unroll
    for (int kk = 0; kk < 4; ++kk)
      qf[kk] = *(const bf16x8*)&src[kk * 32 + quad * 8];
  }

  f32x4 O[4] = {{0.f,0.f,0.f,0.f},{0.f,0.f,0.f,0.f},{0.f,0.f,0.f,0.f},{0.f,0.f,0.f,0.f}};
  float mrow[4] = {-INFINITY, -INFINITY, -INFINITY, -INFINITY};
  float lrow[4] = {0.f, 0.f, 0.f, 0.f};

  #pragma unroll 1
  for (int kt = 0; kt < 16; ++kt) {
    __syncthreads();   // previous tile's readers done (also orders msks on kt=0)
    {
      const unsigned short* ksrc = kplane + (size_t)kt * 8192;
      const unsigned short* vsrc = vplane + (size_t)kt * 4096;
      #pragma unroll
      for (int r = 0; r < 4; ++r)
        async16(&Ks[(r * 256 + tid) * 8], &ksrc[(size_t)(r * 256 + tid) * 8]);
      #pragma unroll
      for (int r = 0; r < 2; ++r)
        async16(&Vs[(r * 256 + tid) * 8], &vsrc[(size_t)(r * 256 + tid) * 8]);
    }
    __syncthreads();   // staged tile visible (drains vmcnt)

    // QK^T: 3-term split (hi·hi + lo·hi + hi·lo); conflict-free lane-contiguous reads
    f32x4 sc[4];
    #pragma unroll
    for (int ns = 0; ns < 4; ++ns) {
      f32x4 c = {0.f, 0.f, 0.f, 0.f};
      bf16x8 kf0 = *(const bf16x8*)&Ks[((ns * 4 + 0) * 64 + lane) * 8];
      bf16x8 kf1 = *(const bf16x8*)&Ks[((ns * 4 + 1) * 64 + lane) * 8];
      bf16x8 kf2 = *(const bf16x8*)&Ks[((ns * 4 + 2) * 64 + lane) * 8];
      bf16x8 kf3 = *(const bf16x8*)&Ks[((ns * 4 + 3) * 64 + lane) * 8];
      c = __builtin_amdgcn_mfma_f32_16x16x32_bf16(qf[0], kf0, c, 0, 0, 0);
      c = __builtin_amdgcn_mfma_f32_16x16x32_bf16(qf[1], kf1, c, 0, 0, 0);
      c = __builtin_amdgcn_mfma_f32_16x16x32_bf16(qf[2], kf0, c, 0, 0, 0);
      c = __builtin_amdgcn_mfma_f32_16x16x32_bf16(qf[3], kf1, c, 0, 0, 0);
      c = __builtin_amdgcn_mfma_f32_16x16x32_bf16(qf[0], kf2, c, 0, 0, 0);
      c = __builtin_amdgcn_mfma_f32_16x16x32_bf16(qf[1], kf3, c, 0, 0, 0);
      sc[ns] = c;
    }

    // mask + scale, row max
    float rmax[4] = {-INFINITY, -INFINITY, -INFINITY, -INFINITY};
    #pragma unroll
    for (int ns = 0; ns < 4; ++ns) {
      float mk = msks[kt * 64 + ns * 16 + l16];
      #pragma unroll
      for (int r = 0; r < 4; ++r) {
        float s = (mk != 0.f) ? -10000.f : sc[ns][r] * 8.f;
        sc[ns][r] = s;
        rmax[r] = fmaxf(rmax[r], s);
      }
    }
    #pragma unroll
    for (int r = 0; r < 4; ++r) {
      float v = rmax[r];
      v = fmaxf(v, __shfl_xor(v, 1, 16));
      v = fmaxf(v, __shfl_xor(v, 2, 16));
      v = fmaxf(v, __shfl_xor(v, 4, 16));
      v = fmaxf(v, __shfl_xor(v, 8, 16));
      rmax[r] = v;
    }

    float alpha[4];
    #pragma unroll
    for (int r = 0; r < 4; ++r) {
      float mn = fmaxf(mrow[r], rmax[r]);
      alpha[r] = __expf(mrow[r] - mn);
      mrow[r] = mn;
      lrow[r] *= alpha[r];
    }
    #pragma unroll
    for (int d = 0; d < 4; ++d)
      #pragma unroll
      for (int r = 0; r < 4; ++r) O[d][r] *= alpha[r];

    // exp, row-sum, write P (bf16) to per-wave LDS in A-fragment order
    float rsum[4] = {0.f, 0.f, 0.f, 0.f};
    #pragma unroll
    for (int ns = 0; ns < 4; ++ns) {
      int key = ns * 16 + l16;
      int cbase = (((key >> 5) * 4 + ((key >> 3) & 3)) * 16 + quad * 4) * 8 + (key & 7);
      #pragma unroll
      for (int r = 0; r < 4; ++r) {
        float p = __expf(sc[ns][r] - mrow[r]);
        rsum[r] += p;
        Pw[wave][cbase + r * 8] = f2bf(p);
      }
    }
    #pragma unroll
    for (int r = 0; r < 4; ++r) {
      float v = rsum[r];
      v += __shfl_xor(v, 1, 16);
      v += __shfl_xor(v, 2, 16);
      v += __shfl_xor(v, 4, 16);
      v += __shfl_xor(v, 8, 16);
      lrow[r] += v;
    }

    // P·V (wave-local; lane-contiguous reads)
    bf16x8 pf[2];
    #pragma unroll
    for (int kk = 0; kk < 2; ++kk)
      pf[kk] = *(const bf16x8*)&Pw[wave][((kk * 4 + quad) * 16 + l16) * 8];
    #pragma unroll
    for (int d = 0; d < 4; ++d)
      #pragma unroll
      for (int kk = 0; kk < 2; ++kk) {
        bf16x8 vf = *(const bf16x8*)&Vs[((d * 2 + kk) * 64 + lane) * 8];
        O[d] = __builtin_amdgcn_mfma_f32_16x16x32_bf16(pf[kk], vf, O[d], 0, 0, 0);
      }
  }

  // epilogue
  const int h = bh & 15;
  #pragma unroll
  for (int r = 0; r < 4; ++r) {
    float inv = 1.f / lrow[r];
    int q = q0 + wave * 16 + quad * 4 + r;
    float* dst = out + ((size_t)bb * Sdim + q) * Hdim + h * HDd;
    #pragma unroll
    for (int d = 0; d < 4; ++d)
      dst[d * 16 + l16] = O[d][r] * inv;
  }
}

extern "C" void kernel_launch(void* const* d_in, const int* in_sizes, int n_in,
                              void* d_out, int out_size, void* d_ws, size_t ws_size,
                              hipStream_t stream) {
  const float* hs   = (const float*)d_in[0];
  const int*   mask = (const int*)d_in[1];
  const float* w    = (const float*)d_in[2];
  const float* bias = (const float*)d_in[3];
  float* out = (float*)d_out;
  unsigned short* ws = (unsigned short*)d_ws;
  unsigned short* ao = (unsigned short*)d_out;   // A hi/lo scratch, overwritten by attn

  convert_AW<<<4096 + (N3H / 64) * (1024 / 64), 256, 0, stream>>>(hs, w, ao, ws);

  qkv_mfma<<<dim3(N3H / 128, 8192 / 128), 256, 0, stream>>>(ao, ws, bias, ws);

  attn_mfma<<<Bdim * NHd * (Sdim / 64), 256, 0, stream>>>(
      ws + Q_OFF, ws + K_OFF, ws + V_OFF, mask, out);
}